// Round 9
// baseline (168.982 us; speedup 1.0000x reference)
//
#include <hip/hip_runtime.h>
#include <hip/hip_bf16.h>

typedef __attribute__((ext_vector_type(8))) short short8;
typedef __attribute__((ext_vector_type(4))) float f32x4;

#define MFMA16(a,b,c) __builtin_amdgcn_mfma_f32_16x16x32_bf16((a),(b),(c),0,0,0)

static __device__ __forceinline__ unsigned int f2bf(float f){
    unsigned int u = __float_as_uint(f);
    u += 0x7FFFu + ((u >> 16) & 1u);
    return u >> 16;
}

static __device__ __forceinline__ short8 pack8(float4 a, float4 b){
    short8 r;
    r[0]=(short)f2bf(a.x); r[1]=(short)f2bf(a.y);
    r[2]=(short)f2bf(a.z); r[3]=(short)f2bf(a.w);
    r[4]=(short)f2bf(b.x); r[5]=(short)f2bf(b.y);
    r[6]=(short)f2bf(b.z); r[7]=(short)f2bf(b.w);
    return r;
}

// ---- mask dtype sniffer: int32 bools are all in {0,1}; byte-bools packed
// into int words set bytes 1..3 somewhere in the first 4096 words.
__global__ void detect_mask_k(const int* __restrict__ m, int* __restrict__ flag){
    __shared__ int any_hi;
    if (threadIdx.x == 0) any_hi = 0;
    __syncthreads();
    int acc = 0;
    #pragma unroll
    for (int it = 0; it < 16; ++it)
        acc |= m[it*256 + threadIdx.x];
    if (acc & 0xFFFFFF00) atomicOr(&any_hi, 1);
    __syncthreads();
    if (threadIdx.x == 0) *flag = any_hi;   // 1 = byte layout, 0 = int32 layout
}

// ---- mask -> bit-packed [b][q][32 words] (1 bit per key, 1 = masked/-inf)
__global__ __launch_bounds__(256) void mask_prep_k(
    const unsigned int* __restrict__ m, const int* __restrict__ flag,
    unsigned int* __restrict__ bmout)
{
    const int tid  = threadIdx.x;
    const int lane = tid & 63;
    const unsigned int gbase = blockIdx.x*256u + tid;
    if (*flag == 0){
        for (int it = 0; it < 32; ++it){
            unsigned int idx = it*262144u + gbase;
            unsigned int v = m[idx];
            unsigned long long bal = __ballot(v != 0u);
            if (lane == 0)
                *(unsigned long long*)(bmout + (idx >> 5)) = bal;
        }
    } else {
        for (int it = 0; it < 8; ++it){
            unsigned int idx = it*262144u + gbase;
            unsigned int v = m[idx];
            unsigned int nib = (v | (v>>7) | (v>>14) | (v>>21)) & 0xFu;
            unsigned int x = nib << ((lane & 7)*4);
            x |= (unsigned int)__shfl_xor((int)x, 1);
            x |= (unsigned int)__shfl_xor((int)x, 2);
            x |= (unsigned int)__shfl_xor((int)x, 4);
            if ((lane & 7) == 0)
                bmout[idx >> 3] = x;
        }
    }
}

// ---------------- QKV projection (3-way split grid) ----------------
__global__ __launch_bounds__(256) void qkv_proj_k(
    const float* __restrict__ nd,
    const float* __restrict__ Wqp, const float* __restrict__ bqp,
    const float* __restrict__ Wkp, const float* __restrict__ bkp,
    const float* __restrict__ Wvp, const float* __restrict__ bvp,
    unsigned short* __restrict__ qout, unsigned short* __restrict__ kout,
    unsigned short* __restrict__ vtout)
{
    __shared__ __align__(16) unsigned short xl[64*264];
    const int tid  = threadIdx.x;
    const int bi   = blockIdx.x;          // 384 = 3 kinds x 128 tiles
    const int kind = bi >> 7;
    const int R0   = (bi & 127) * 64;
    const int b    = R0 >> 10;
    const int n0   = R0 & 1023;

    #pragma unroll
    for (int it = 0; it < 16; ++it){
        int f4 = it*256 + tid;
        int r = f4 >> 6, c4 = f4 & 63;
        float4 v = *(const float4*)(nd + (size_t)(R0+r)*256 + c4*4);
        unsigned int lo = f2bf(v.x) | (f2bf(v.y) << 16);
        unsigned int hi = f2bf(v.z) | (f2bf(v.w) << 16);
        *(uint2*)&xl[r*264 + c4*4] = make_uint2(lo, hi);
    }
    __syncthreads();

    const int lane = tid & 63;
    const int w  = tid >> 6;
    const int ln = lane & 15;
    const int g  = lane >> 4;
    const int ow = w * 64;

    f32x4 acc[4][4];
    #pragma unroll
    for (int a=0;a<4;++a){
        #pragma unroll
        for (int c=0;c<4;++c) acc[a][c] = (f32x4){0.f,0.f,0.f,0.f};
    }

    if (kind < 2){
        const float* W  = kind ? Wkp : Wqp;
        const float* bb = kind ? bkp : bqp;
        unsigned short* op = kind ? kout : qout;
        const float scl = kind ? 1.0f : 0.17677669529663687f;
        for (int kk = 0; kk < 8; ++kk){
            short8 wf[4], xf[4];
            #pragma unroll
            for (int ot=0; ot<4; ++ot){
                const float* wp = W + (size_t)(ow + ot*16 + ln)*256 + kk*32 + g*8;
                wf[ot] = pack8(*(const float4*)wp, *(const float4*)(wp+4));
            }
            #pragma unroll
            for (int nt=0; nt<4; ++nt)
                xf[nt] = *(const short8*)&xl[(nt*16+ln)*264 + kk*32 + g*8];
            #pragma unroll
            for (int ot=0; ot<4; ++ot){
                #pragma unroll
                for (int nt=0; nt<4; ++nt)
                    acc[ot][nt] = MFMA16(wf[ot], xf[nt], acc[ot][nt]);
            }
        }
        #pragma unroll
        for (int ot=0; ot<4; ++ot){
            int o0 = ow + ot*16 + g*4;
            int h = o0 >> 5, d0 = o0 & 31;
            float4 b4 = *(const float4*)(bb + o0);
            #pragma unroll
            for (int nt=0; nt<4; ++nt){
                int n = n0 + nt*16 + ln;
                unsigned int lo = f2bf((acc[ot][nt][0]+b4.x)*scl) | (f2bf((acc[ot][nt][1]+b4.y)*scl)<<16);
                unsigned int hi = f2bf((acc[ot][nt][2]+b4.z)*scl) | (f2bf((acc[ot][nt][3]+b4.w)*scl)<<16);
                *(uint2*)(op + ((size_t)(b*8+h)*1024 + n)*32 + d0) = make_uint2(lo,hi);
            }
        }
    } else {
        for (int kk = 0; kk < 8; ++kk){
            short8 wf[4], xf[4];
            #pragma unroll
            for (int ot=0; ot<4; ++ot){
                const float* wp = Wvp + (size_t)(ow + ot*16 + ln)*256 + kk*32 + g*8;
                wf[ot] = pack8(*(const float4*)wp, *(const float4*)(wp+4));
            }
            #pragma unroll
            for (int nt=0; nt<4; ++nt)
                xf[nt] = *(const short8*)&xl[(nt*16+ln)*264 + kk*32 + g*8];
            #pragma unroll
            for (int nt=0; nt<4; ++nt){
                #pragma unroll
                for (int ot=0; ot<4; ++ot)
                    acc[nt][ot] = MFMA16(xf[nt], wf[ot], acc[nt][ot]);
            }
        }
        #pragma unroll
        for (int nt=0; nt<4; ++nt){
            int nb = n0 + nt*16 + g*4;
            #pragma unroll
            for (int ot=0; ot<4; ++ot){
                int o = ow + ot*16 + ln;
                int h = o >> 5, d = o & 31;
                float bvv = bvp[o];
                unsigned int lo = f2bf(acc[nt][ot][0]+bvv) | (f2bf(acc[nt][ot][1]+bvv)<<16);
                unsigned int hi = f2bf(acc[nt][ot][2]+bvv) | (f2bf(acc[nt][ot][3]+bvv)<<16);
                *(uint2*)(vtout + ((size_t)(b*8+h)*32 + d)*1024 + nb) = make_uint2(lo,hi);
            }
        }
    }
}

// ---------------- Fused biased-masked attention (split-K x4) ----------------
// Grid 2048 = kq(4) x b(8) x qtile(64). Block: 256 thr = 4 waves, 2 heads/wave,
// 16 q rows, 8 key-chunks of 32. Key-permuted K rows make S^T's per-lane keys
// equal the PV B-frag keys (8g..8g+7) -> ZERO shuffles for P. Bias tile in LDS
// as [q][h][key] (stride 264): per-lane 8 contiguous floats -> 2x b128 reads.
// Fixed-max softmax -> split-K partials are exactly additive (no max merge).
__global__ __launch_bounds__(256, 4) void attn_k(
    const unsigned short* __restrict__ qbuf, const unsigned short* __restrict__ kbuf,
    const unsigned short* __restrict__ vtbuf, const float* __restrict__ bias,
    const unsigned int* __restrict__ bm, float* __restrict__ opart,
    float* __restrict__ lpart)
{
    __shared__ __align__(16) float bs[16*264];   // 16.5 KB, single buffer
    const int tid  = threadIdx.x;
    const int bi   = blockIdx.x;
    const int kq   = bi >> 9;           // 0..3: key quarter
    const int b    = (bi >> 6) & 7;
    const int q0   = (bi & 63) * 16;
    const int lane = tid & 63;
    const int w    = tid >> 6;
    const int ln   = lane & 15;
    const int g    = lane >> 4;
    const int h0   = w*2, h1 = w*2+1;
    const int cbase = kq*8;             // first chunk index

    // Q frags (B-operand: col=q=ln, k=d=g*8..)
    const short8 qf0 = *(const short8*)(qbuf + ((size_t)(b*8+h0)*1024 + q0 + ln)*32 + g*8);
    const short8 qf1 = *(const short8*)(qbuf + ((size_t)(b*8+h1)*1024 + q0 + ln)*32 + g*8);

    // K row permutation: tile t row ln -> key 8*(ln>>2)+(ln&3)+4t
    const int kperm = ((ln >> 2) << 3) + (ln & 3);
    const unsigned short* kp0 = kbuf + ((size_t)(b*8+h0)*1024 + kperm)*32 + g*8;
    const unsigned short* kp1 = kbuf + ((size_t)(b*8+h1)*1024 + kperm)*32 + g*8;
    const unsigned short* vp0 = vtbuf + ((size_t)(b*8+h0)*32 + ln)*1024 + g*8;
    const unsigned short* vp1 = vtbuf + ((size_t)(b*8+h1)*32 + ln)*1024 + g*8;
    const unsigned int*  bmp = bm + (size_t)(b*1024 + q0 + ln)*32;

    // staging decode: thread covers (q = it*4 + tid>>6, k = (tid&63)>>1, hb = (tid&1)*4)
    const int sq  = tid >> 6;
    const int sk  = (tid & 63) >> 1;
    const int shb = (tid & 1) * 4;
    const float* bgp = bias + ((size_t)(b*1024 + q0 + sq)*1024 + sk)*8 + shb;
    const int lwb = sq*264 + shb*32 + sk;            // LDS write base (floats)
    // bias read base per head: [q=ln][h][key=8g..]
    const int brd0 = ln*264 + h0*32 + g*8;
    const int brd1 = ln*264 + h1*32 + g*8;

    f32x4 acc[4];   // [h2*2+t]: O^T rows t*16+g*4+r, col q=ln
    #pragma unroll
    for (int i=0;i<4;++i) acc[i] = (f32x4){0.f,0.f,0.f,0.f};
    float lsum[2] = {0.f, 0.f};
    const f32x4 z4 = {0.f,0.f,0.f,0.f};

    float4 br[4];
    short8 kA[4], kB[4], vv[4];
    unsigned int bmA, bmB;

#define LOAD_BIAS(cc) do { int c_=(cc); \
    _Pragma("unroll") for (int it_=0; it_<4; ++it_) \
        br[it_] = *(const float4*)(bgp + (size_t)it_*32768 + c_*256); } while(0)

#define STAGE() do { \
    _Pragma("unroll") for (int it_=0; it_<4; ++it_){ \
        bs[lwb + it_*1056      ] = br[it_].x; \
        bs[lwb + it_*1056 +  32] = br[it_].y; \
        bs[lwb + it_*1056 +  64] = br[it_].z; \
        bs[lwb + it_*1056 +  96] = br[it_].w; } } while(0)

#define LOAD_K(DST, cc) do { int c_=(cc); \
    DST[0] = *(const short8*)(kp0 + c_*1024);        \
    DST[1] = *(const short8*)(kp0 + c_*1024 + 128);  \
    DST[2] = *(const short8*)(kp1 + c_*1024);        \
    DST[3] = *(const short8*)(kp1 + c_*1024 + 128); } while(0)

#define LOAD_V(cc) do { int c_=(cc); \
    vv[0] = *(const short8*)(vp0 + c_*32);           \
    vv[1] = *(const short8*)(vp0 + c_*32 + 16*1024); \
    vv[2] = *(const short8*)(vp1 + c_*32);           \
    vv[3] = *(const short8*)(vp1 + c_*32 + 16*1024); } while(0)

#define COMPUTE(KARR, BMW) do { \
    unsigned int mb_ = (BMW) >> (g*8); \
    _Pragma("unroll") for (int h2=0; h2<2; ++h2){ \
        f32x4 s0 = MFMA16(KARR[h2*2+0], (h2 ? qf1 : qf0), z4); \
        f32x4 s1 = MFMA16(KARR[h2*2+1], (h2 ? qf1 : qf0), z4); \
        const float* bb_ = &bs[h2 ? brd1 : brd0]; \
        float4 b0 = *(const float4*)bb_; \
        float4 b1 = *(const float4*)(bb_ + 4); \
        float e0 = __expf(((mb_>>0)&1u) ? -1e30f : s0[0]+b0.x); \
        float e1 = __expf(((mb_>>1)&1u) ? -1e30f : s0[1]+b0.y); \
        float e2 = __expf(((mb_>>2)&1u) ? -1e30f : s0[2]+b0.z); \
        float e3 = __expf(((mb_>>3)&1u) ? -1e30f : s0[3]+b0.w); \
        float e4 = __expf(((mb_>>4)&1u) ? -1e30f : s1[0]+b1.x); \
        float e5 = __expf(((mb_>>5)&1u) ? -1e30f : s1[1]+b1.y); \
        float e6 = __expf(((mb_>>6)&1u) ? -1e30f : s1[2]+b1.z); \
        float e7 = __expf(((mb_>>7)&1u) ? -1e30f : s1[3]+b1.w); \
        lsum[h2] += ((e0+e1)+(e2+e3)) + ((e4+e5)+(e6+e7)); \
        int4 pw_ = make_int4( \
            (int)(f2bf(e0) | (f2bf(e1)<<16)), (int)(f2bf(e2) | (f2bf(e3)<<16)), \
            (int)(f2bf(e4) | (f2bf(e5)<<16)), (int)(f2bf(e6) | (f2bf(e7)<<16))); \
        short8 pf_ = *(short8*)&pw_; \
        acc[h2*2+0] = MFMA16(vv[h2*2+0], pf_, acc[h2*2+0]); \
        acc[h2*2+1] = MFMA16(vv[h2*2+1], pf_, acc[h2*2+1]); \
    } } while(0)

    // prologue
    LOAD_BIAS(cbase);
    LOAD_K(kA, cbase);
    bmA = bmp[cbase];
    if (kq == 0) bmA &= ~1u;            // col 0 force-unmasked (chunk 0 only)

    #pragma unroll 1
    for (int cc = 0; cc < 8; cc += 2){
        int c = cbase + cc;
        // even chunk
        STAGE();
        LOAD_BIAS(c + 1);
        __syncthreads();
        LOAD_V(c);
        LOAD_K(kB, c + 1);
        bmB = bmp[c + 1];
        COMPUTE(kA, bmA);
        __syncthreads();
        // odd chunk
        STAGE();
        if (cc + 2 < 8) LOAD_BIAS(c + 2);
        __syncthreads();
        LOAD_V(c + 1);
        if (cc + 2 < 8){ LOAD_K(kA, c + 2); bmA = bmp[c + 2]; }
        COMPUTE(kB, bmB);
        __syncthreads();
    }

    // epilogue: write unnormalized partials + denominators
    #pragma unroll
    for (int h2 = 0; h2 < 2; ++h2){
        float ps = lsum[h2];
        ps += __shfl_xor(ps, 16);
        ps += __shfl_xor(ps, 32);
        size_t row = ((size_t)(kq*8 + b)*1024 + q0 + ln)*8 + (w*2 + h2);
        if (g == 0) lpart[row] = ps;
        float* ob = opart + row*32;
        *(float4*)(ob + g*4)      = make_float4(acc[h2*2][0],   acc[h2*2][1],   acc[h2*2][2],   acc[h2*2][3]);
        *(float4*)(ob + 16 + g*4) = make_float4(acc[h2*2+1][0], acc[h2*2+1][1], acc[h2*2+1][2], acc[h2*2+1][3]);
    }
#undef LOAD_BIAS
#undef STAGE
#undef LOAD_K
#undef LOAD_V
#undef COMPUTE
}

// ---------------- split-K combine: ab = (sum Opart) / (sum l) ----------------
__global__ __launch_bounds__(256) void combine_k(
    const float* __restrict__ op, const float* __restrict__ lp,
    unsigned short* __restrict__ ab)
{
    const size_t STR = (size_t)8*1024*8*32;   // 2M floats per partial
    int idx = blockIdx.x*256 + threadIdx.x;   // float4 index, 524288 total
    size_t off = (size_t)idx * 4;
    float4 s0 = *(const float4*)(op + off);
    float4 s1 = *(const float4*)(op + STR + off);
    float4 s2 = *(const float4*)(op + 2*STR + off);
    float4 s3 = *(const float4*)(op + 3*STR + off);
    int bqh = idx >> 3;                        // (b*1024+q)*8+h
    float l = lp[bqh] + lp[65536 + bqh] + lp[2*65536 + bqh] + lp[3*65536 + bqh];
    float inv = 1.0f / l;
    float rx = (s0.x + s1.x + s2.x + s3.x) * inv;
    float ry = (s0.y + s1.y + s2.y + s3.y) * inv;
    float rz = (s0.z + s1.z + s2.z + s3.z) * inv;
    float rw = (s0.w + s1.w + s2.w + s3.w) * inv;
    unsigned int lo = f2bf(rx) | (f2bf(ry) << 16);
    unsigned int hi = f2bf(rz) | (f2bf(rw) << 16);
    *(uint2*)(ab + off) = make_uint2(lo, hi);
}

// ---------------- Output projection (32-row tiles) ----------------
__global__ __launch_bounds__(256) void oproj_k(
    const unsigned short* __restrict__ ab, const float* __restrict__ Wop,
    const float* __restrict__ bop, float* __restrict__ out)
{
    __shared__ __align__(16) unsigned short al[32*264];
    const int tid = threadIdx.x;
    const int R0 = blockIdx.x * 32;   // 256 blocks
    #pragma unroll
    for (int it=0; it<4; ++it){
        int f8 = it*256 + tid;
        int r = f8 >> 5, c8 = f8 & 31;
        *(short8*)&al[r*264 + c8*8] = *(const short8*)(ab + (size_t)(R0+r)*256 + c8*8);
    }
    __syncthreads();
    const int lane = tid & 63;
    const int w = tid >> 6, ln = lane & 15, g = lane >> 4;
    const int ow = w*64;
    f32x4 acc[4][2];
    #pragma unroll
    for (int a=0;a<4;++a){ acc[a][0]=(f32x4){0.f,0.f,0.f,0.f}; acc[a][1]=(f32x4){0.f,0.f,0.f,0.f}; }
    for (int kk=0;kk<8;++kk){
        short8 wf[4], xf[2];
        #pragma unroll
        for (int ot=0;ot<4;++ot){
            const float* wp = Wop + (size_t)(ow+ot*16+ln)*256 + kk*32 + g*8;
            wf[ot] = pack8(*(const float4*)wp, *(const float4*)(wp+4));
        }
        #pragma unroll
        for (int nt=0;nt<2;++nt)
            xf[nt] = *(const short8*)&al[(nt*16+ln)*264 + kk*32 + g*8];
        #pragma unroll
        for (int ot=0;ot<4;++ot){
            #pragma unroll
            for (int nt=0;nt<2;++nt)
                acc[ot][nt] = MFMA16(wf[ot], xf[nt], acc[ot][nt]);
        }
    }
    #pragma unroll
    for (int ot=0;ot<4;++ot){
        int o0 = ow + ot*16 + g*4;
        float4 b4 = *(const float4*)(bop + o0);
        #pragma unroll
        for (int nt=0;nt<2;++nt){
            int n = R0 + nt*16 + ln;
            float4 res;
            res.x = acc[ot][nt][0] + b4.x;
            res.y = acc[ot][nt][1] + b4.y;
            res.z = acc[ot][nt][2] + b4.z;
            res.w = acc[ot][nt][3] + b4.w;
            *(float4*)(out + (size_t)n*256 + o0) = res;
        }
    }
}

extern "C" void kernel_launch(void* const* d_in, const int* in_sizes, int n_in,
                              void* d_out, int out_size, void* d_ws, size_t ws_size,
                              hipStream_t stream)
{
    (void)in_sizes; (void)n_in; (void)out_size; (void)ws_size;
    const float* nd   = (const float*)d_in[0];
    // d_in[1] = N scalar (compile-time 1024 here)
    const float* bias = (const float*)d_in[2];
    const int* mask   = (const int*)d_in[3];
    const float* Wq = (const float*)d_in[4];
    const float* bq = (const float*)d_in[5];
    const float* Wk = (const float*)d_in[6];
    const float* bk = (const float*)d_in[7];
    const float* Wv = (const float*)d_in[8];
    const float* bv = (const float*)d_in[9];
    const float* Wo = (const float*)d_in[10];
    const float* bo = (const float*)d_in[11];
    float* out = (float*)d_out;

    const size_t ELEMS = (size_t)8*8*1024*32;   // 2M bf16 per buffer
    unsigned short* qb  = (unsigned short*)d_ws;
    unsigned short* kb  = qb  + ELEMS;
    unsigned short* vtb = kb  + ELEMS;
    unsigned short* ab  = vtb + ELEMS;
    unsigned int* bmw   = (unsigned int*)(ab + ELEMS);     // 1MB bitmask
    float* opart        = (float*)(bmw + 262144);          // 4 x 2M f32 = 32MB
    float* lpart        = opart + (size_t)4*ELEMS;         // 4 x 64K f32 = 1MB
    int* mflag          = (int*)(lpart + 4*65536);

    detect_mask_k<<<1, 256, 0, stream>>>(mask, mflag);
    mask_prep_k<<<1024, 256, 0, stream>>>((const unsigned int*)mask, mflag, bmw);
    qkv_proj_k<<<384, 256, 0, stream>>>(nd, Wq, bq, Wk, bk, Wv, bv, qb, kb, vtb);
    attn_k<<<2048, 256, 0, stream>>>(qb, kb, vtb, bias, bmw, opart, lpart);
    combine_k<<<2048, 256, 0, stream>>>(opart, lpart, ab);
    oproj_k<<<256, 256, 0, stream>>>(ab, Wo, bo, out);
}